// Round 7
// baseline (53.130 us; speedup 1.0000x reference)
//
#include <hip/hip_runtime.h>
#include <hip/hip_bf16.h>

// Shapes: keypoints (8,5,2) f32, mesh_grid (1024,2) f32, W (10,512) f32,
// distance_matrix (1024,1024) i32 in [0,64). Output (8,8,1024,1024) f32.
//
// Reshape semantics: A (B,N,512) -> (B,8,N,64) row-major raw reshape:
//   n_orig = h*128 + (n_new>>3);  o = (n_new&7)*64 + k
// out[b,h,n,m] = A_new[b,h,n, dm[n,m]]
//
// R7 = R5(nt stores, reverted from R6's plain-store regression) + row
// batching: one wave = 4 consecutive rows of one plane = 16 KB contiguous
// nt stream (rows are adjacent within a plane). Grid 4096 = 16 plane-groups
// x 256 row-groups, row-group fast so consecutive blocks extend the same 4
// planes' streams. Table per row in one register (k = lane); ds_bpermute
// gather (conflict-free).

#define NN 1024

typedef float f32x4 __attribute__((ext_vector_type(4)));

__global__ __launch_bounds__(256) void KR_RPE_10582799417497_kernel(
    const float* __restrict__ kp,    // (8,5,2)
    const float* __restrict__ mesh,  // (1024,2)
    const float* __restrict__ W,     // (10,512)
    const int*   __restrict__ dm,    // (1024,1024)
    float* __restrict__ out)         // (8,8,1024,1024)
{
    const int bid  = blockIdx.x;
    const int g    = bid >> 8;        // plane group 0..15 (slow)
    const int nb   = (bid & 255) * 4; // base row (fast)
    const int t    = threadIdx.x;
    const int lane = t & 63;
    const int w    = t >> 6;          // wave 0..3
    const int bh   = g * 4 + w;       // this wave's output plane
    const int b    = bh >> 3, h = bh & 7;
    const int k    = lane;            // this lane's table column

    // keypoints for b: 10 floats, hoisted (wave-uniform)
    float kx[5], ky[5];
#pragma unroll
    for (int p = 0; p < 5; ++p) {
        kx[p] = kp[b * 10 + p * 2 + 0];
        ky[p] = kp[b * 10 + p * 2 + 1];
    }

    float* plane = out + (size_t)bh * NN * NN;

#pragma unroll
    for (int r = 0; r < 4; ++r) {
        const int n  = nb + r;
        const int n0 = n >> 3;
        const int oo = (n & 7) * 64;

        // W column slice for this row's o-base (coalesced 256 B per load)
        float Wv[10];
#pragma unroll
        for (int f = 0; f < 10; ++f) Wv[f] = W[f * 512 + oo + k];

        const int n_orig = h * 128 + n0;
        const float mx = mesh[n_orig * 2 + 0];
        const float my = mesh[n_orig * 2 + 1];
        float acc = 0.f;
#pragma unroll
        for (int p = 0; p < 5; ++p)
            acc += (mx - kx[p]) * Wv[p * 2 + 0] + (my - ky[p]) * Wv[p * 2 + 1];
        const int s = __float_as_int(acc);

        const int* dr = dm + (size_t)n * NN;
        float* op = plane + (size_t)n * NN;

#pragma unroll
        for (int it = 0; it < 4; ++it) {
            const int4 kk = *(const int4*)(dr + it * 256 + lane * 4);
            f32x4 v;
            v.x = __int_as_float(__builtin_amdgcn_ds_bpermute(kk.x * 4, s));
            v.y = __int_as_float(__builtin_amdgcn_ds_bpermute(kk.y * 4, s));
            v.z = __int_as_float(__builtin_amdgcn_ds_bpermute(kk.z * 4, s));
            v.w = __int_as_float(__builtin_amdgcn_ds_bpermute(kk.w * 4, s));
            __builtin_nontemporal_store(v, (f32x4*)(op + it * 256 + lane * 4));
        }
    }
}

extern "C" void kernel_launch(void* const* d_in, const int* in_sizes, int n_in,
                              void* d_out, int out_size, void* d_ws, size_t ws_size,
                              hipStream_t stream) {
    const float* kp   = (const float*)d_in[0];
    const float* mesh = (const float*)d_in[1];
    const float* W    = (const float*)d_in[2];
    const int*   dm   = (const int*)d_in[3];
    float* out = (float*)d_out;

    KR_RPE_10582799417497_kernel<<<16 * 256, 256, 0, stream>>>(kp, mesh, W, dm, out);
}